// Round 6
// baseline (510.520 us; speedup 1.0000x reference)
//
#include <hip/hip_runtime.h>

typedef __bf16 bf16x8 __attribute__((ext_vector_type(8)));
typedef float f32x4 __attribute__((ext_vector_type(4)));

#define NEG_SLOPE 0.01f
#define BN_EPS 1e-5f

static __device__ __forceinline__ unsigned short f2bf(float f) {
    unsigned u = __builtin_bit_cast(unsigned, f);
    unsigned r = (u + 0x7fffu + ((u >> 16) & 1u)) >> 16;
    return (unsigned short)r;
}
static __device__ __forceinline__ float lrelu(float v) {
    return fmaxf(v, 0.f) + NEG_SLOPE * fminf(v, 0.f);
}
static __device__ __forceinline__ f32x4 bn4(f32x4 v, f32x4 sc, f32x4 sh) {
    f32x4 r = v * sc + sh;
    r.x = lrelu(r.x); r.y = lrelu(r.y); r.z = lrelu(r.z); r.w = lrelu(r.w);
    return r;
}

// ---- prep: convert ef to bf16 AND swizzle W_edge{0,1} into fragment order ----
// wbs[i][os][h][l][k] (shorts): lane l of o-slice os reads a CONTIGUOUS 16B
// A-frag: o = 16*os + (l&15), d = h*32 + 8*(l>>4) + k. 1KiB coalesced per wave.
__global__ __launch_bounds__(256) void prep(const float* __restrict__ ef,
                                            unsigned short* __restrict__ ef_b, int na4,
                                            const float* __restrict__ We0,
                                            const float* __restrict__ We1,
                                            unsigned short* __restrict__ wbs0,
                                            unsigned short* __restrict__ wbs1,
                                            float* __restrict__ stats,
                                            int* __restrict__ counters) {
    const int idx = blockIdx.x * 256 + threadIdx.x;
    if (blockIdx.x == 0) {
        stats[threadIdx.x] = 0.f;                  // stats[0..255]
        if (threadIdx.x < 2) counters[threadIdx.x] = 0;
    }
    if (idx < na4) {
        const f32x4 v = *reinterpret_cast<const f32x4*>(ef + (size_t)idx * 4);
        ushort4 u;
        u.x = f2bf(v.x); u.y = f2bf(v.y); u.z = f2bf(v.z); u.w = f2bf(v.w);
        *reinterpret_cast<ushort4*>(ef_b + (size_t)idx * 4) = u;
    } else {
        const int t = idx - na4;                   // 0..65535
        const float* We = (t >> 15) ? We1 : We0;
        unsigned short* wbs = (t >> 15) ? wbs1 : wbs0;
        const int r = t & 32767;                   // [i:6][os:2][h:1][l:6]
        const int i = r >> 9, os = (r >> 7) & 3, h = (r >> 6) & 1, l = r & 63;
        const float* sp = We + (size_t)(i * 64 + 16 * os + (l & 15)) * 64
                             + h * 32 + 8 * (l >> 4);
        const f32x4 v0 = *reinterpret_cast<const f32x4*>(sp);
        const f32x4 v1 = *reinterpret_cast<const f32x4*>(sp + 4);
        ushort4 u0, u1;
        u0.x = f2bf(v0.x); u0.y = f2bf(v0.y); u0.z = f2bf(v0.z); u0.w = f2bf(v0.w);
        u1.x = f2bf(v1.x); u1.y = f2bf(v1.y); u1.z = f2bf(v1.z); u1.w = f2bf(v1.w);
        *reinterpret_cast<ushort4*>(wbs + (size_t)r * 8) = u0;
        *reinterpret_cast<ushort4*>(wbs + (size_t)r * 8 + 4) = u1;
    }
}

// ---- root + node-bias matmuls; optional BN(x) on load ----
// y=0: aggr = BN(x)@Wr + br ; y=1: NB = BN(x)@be
__global__ __launch_bounds__(256) void node_mm2(const float* __restrict__ x,
                                                const float* __restrict__ Wr,
                                                const float* __restrict__ br,
                                                float* __restrict__ aggr,
                                                const float* __restrict__ be,
                                                float* __restrict__ NB,
                                                const float* __restrict__ ss) {
    const float* M; const float* bias; float* out;
    if (blockIdx.y == 0) { M = Wr; bias = br; out = aggr; }
    else                 { M = be; bias = nullptr; out = NB; }
    __shared__ float Ml[64][64];
    __shared__ float xl[64][64];
    const int tid = threadIdx.x;
    const int n0 = blockIdx.x * 64;
    for (int f = tid; f < 1024; f += 256) {
        int r = f >> 4, c = f & 15;
        *reinterpret_cast<float4*>(&Ml[r][c * 4]) =
            *reinterpret_cast<const float4*>(M + (size_t)r * 64 + c * 4);
        f32x4 xv = *reinterpret_cast<const f32x4*>(x + (size_t)(n0 + r) * 64 + c * 4);
        if (ss) {
            const f32x4 sc = *reinterpret_cast<const f32x4*>(ss + c * 4);
            const f32x4 sh = *reinterpret_cast<const f32x4*>(ss + 64 + c * 4);
            xv = bn4(xv, sc, sh);
        }
        *reinterpret_cast<f32x4*>(&xl[r][c * 4]) = xv;
    }
    __syncthreads();
    const int o = tid & 63, g = tid >> 6;
    float acc[16] = {};
    for (int i4 = 0; i4 < 16; ++i4) {
        float m0 = Ml[4 * i4 + 0][o], m1 = Ml[4 * i4 + 1][o];
        float m2 = Ml[4 * i4 + 2][o], m3 = Ml[4 * i4 + 3][o];
#pragma unroll
        for (int k = 0; k < 16; ++k) {
            const f32x4 xv = *reinterpret_cast<const f32x4*>(&xl[g + 4 * k][4 * i4]);
            acc[k] += xv.x * m0 + xv.y * m1 + xv.z * m2 + xv.w * m3;
        }
    }
    const float b = bias ? bias[o] : 0.f;
#pragma unroll
    for (int k = 0; k < 16; ++k)
        out[(size_t)(n0 + g + 4 * k) * 64 + o] = acc[k] + b;
}

// ---- fused NNConv message, o-split + fragment-order W (coalesced A-loads) ----
// Block = 64 edges x o-slice [16*by, 16*by+16). Wave w = 16-edge tile.
// Per i: D_i[o,e] = sum_d W_i[o,d]*ef[e,d] (2 MFMA); acc += x[src[e],i]*D_i.
__global__ __launch_bounds__(256, 6) void msg_fused(
    const unsigned short* __restrict__ ef_b,   // [E][64] bf16
    const unsigned short* __restrict__ wbs,    // fragment-order, see prep
    const float* __restrict__ x,               // [N][64] f32 (pre-BN if ss)
    const float* __restrict__ NB,              // [N][64] f32
    const int* __restrict__ src,
    const int* __restrict__ dst,
    float* __restrict__ aggr,                  // [N][64] f32
    const float* __restrict__ ss) {            // BN scale/shift for x, or null
    __shared__ float xT[64][64];               // xT[i][e] = BN(x)[src[e]][i]
    const int tid = threadIdx.x;
    const int e0 = blockIdx.x * 64;
    const int os = blockIdx.y;
    const int O0 = os * 16;

    // gather x rows of the 64 src nodes, transposed (f32, exact; BN on load)
#pragma unroll
    for (int it = 0; it < 4; ++it) {
        int f = it * 256 + tid;
        int e = f & 63, c = f >> 6;            // c in 0..15
        int s = src[e0 + e];
        f32x4 xv = *reinterpret_cast<const f32x4*>(x + (size_t)s * 64 + c * 4);
        if (ss) {
            const f32x4 sc = *reinterpret_cast<const f32x4*>(ss + c * 4);
            const f32x4 sh = *reinterpret_cast<const f32x4*>(ss + 64 + c * 4);
            xv = bn4(xv, sc, sh);
        }
        xT[4 * c + 0][e] = xv.x;
        xT[4 * c + 1][e] = xv.y;
        xT[4 * c + 2][e] = xv.z;
        xT[4 * c + 3][e] = xv.w;
    }

    const int w = tid >> 6, l = tid & 63, lg = l >> 4, ln = l & 15;
    const int ecol = 16 * w + ln;              // this lane's edge column

    // ef B-frag: wave's single 16-edge tile
    const unsigned short* pe = ef_b + (size_t)(e0 + ecol) * 64 + 8 * lg;
    const bf16x8 B0 = *reinterpret_cast<const bf16x8*>(pe);
    const bf16x8 B1 = *reinterpret_cast<const bf16x8*>(pe + 32);

    // W A-frags: contiguous 16B per lane, 1KiB per wave-load; 4-deep prefetch
    const unsigned short* pwA = wbs + (size_t)os * 1024 + l * 8;   // i-stride 4096
    bf16x8 A0[4], A1[4];
#pragma unroll
    for (int p = 0; p < 4; ++p) {
        A0[p] = *reinterpret_cast<const bf16x8*>(pwA + (size_t)p * 4096);
        A1[p] = *reinterpret_cast<const bf16x8*>(pwA + (size_t)p * 4096 + 512);
    }

    __syncthreads();

    f32x4 acc = {};
#pragma unroll
    for (int i = 0; i < 64; ++i) {
        f32x4 c = {};
        c = __builtin_amdgcn_mfma_f32_16x16x32_bf16(A0[i & 3], B0, c, 0, 0, 0);
        c = __builtin_amdgcn_mfma_f32_16x16x32_bf16(A1[i & 3], B1, c, 0, 0, 0);
        if (i < 60) {
            A0[i & 3] = *reinterpret_cast<const bf16x8*>(pwA + (size_t)(i + 4) * 4096);
            A1[i & 3] = *reinterpret_cast<const bf16x8*>(pwA + (size_t)(i + 4) * 4096 + 512);
        }
        acc += xT[i][ecol] * c;
    }

    // epilogue: add NB[src][o-slice], scatter to aggr[dst][o-slice]
    const int e = e0 + ecol;
    const int s = src[e], d = dst[e];
    const f32x4 nbv = *reinterpret_cast<const f32x4*>(NB + (size_t)s * 64 + O0 + 4 * lg);
    const f32x4 add = acc + nbv;
#pragma unroll
    for (int rr = 0; rr < 4; ++rr)
        atomicAdd(aggr + (size_t)d * 64 + O0 + 4 * lg + rr, add[rr]);
}

// ---- BN statistics + last-block finalize (computes ss scale/shift) ----
__global__ __launch_bounds__(256) void bn_stats(const float* __restrict__ h,
                                                float* __restrict__ sums,
                                                const float* __restrict__ gamma,
                                                const float* __restrict__ beta,
                                                float* __restrict__ ss,
                                                float invN,
                                                int* __restrict__ counter,
                                                int nblk) {
    const int tid = threadIdx.x;
    const int o = tid & 63, g = tid >> 6;
    const int n0 = blockIdx.x * 128;
    float s = 0.f, s2 = 0.f;
    for (int k = 0; k < 32; ++k) {
        float v = h[(size_t)(n0 + g * 32 + k) * 64 + o];
        s += v; s2 += v * v;
    }
    __shared__ float red[2][4][64];
    __shared__ int lastFlag;
    red[0][g][o] = s; red[1][g][o] = s2;
    __syncthreads();
    if (g == 0) {
        s  = red[0][0][o] + red[0][1][o] + red[0][2][o] + red[0][3][o];
        s2 = red[1][0][o] + red[1][1][o] + red[1][2][o] + red[1][3][o];
        atomicAdd(&sums[o], s);
        atomicAdd(&sums[64 + o], s2);
    }
    __threadfence();
    __syncthreads();
    if (tid == 0) lastFlag = (atomicAdd(counter, 1) == nblk - 1);
    __syncthreads();
    if (lastFlag && tid < 64) {
        const float sv  = atomicAdd(&sums[tid], 0.f);        // coherent read
        const float sv2 = atomicAdd(&sums[64 + tid], 0.f);
        const float mean = sv * invN;
        const float var  = sv2 * invN - mean * mean;
        const float sc = gamma[tid] * rsqrtf(var + BN_EPS);
        ss[tid] = sc;
        ss[64 + tid] = beta[tid] - mean * sc;
    }
}

// ---- final: out[n,q] = sum_o BN(x)[n,o]*W_lin[q,o] + b_lin[q] ----
__global__ __launch_bounds__(256) void out_kernel(const float* __restrict__ x2,
                                                  const float* __restrict__ Wl,
                                                  const float* __restrict__ bl,
                                                  float* __restrict__ out,
                                                  const float* __restrict__ ss) {
    __shared__ float Wt[64][129];
    __shared__ float xl[64][64];
    const int tid = threadIdx.x;
    const int n0 = blockIdx.x * 64;
    for (int f = tid; f < 8192; f += 256) {
        int q = f >> 6, o = f & 63;
        Wt[o][q] = Wl[f];
    }
    for (int f = tid; f < 1024; f += 256) {
        int r = f >> 4, c = f & 15;
        f32x4 xv = *reinterpret_cast<const f32x4*>(x2 + (size_t)(n0 + r) * 64 + c * 4);
        const f32x4 sc = *reinterpret_cast<const f32x4*>(ss + c * 4);
        const f32x4 sh = *reinterpret_cast<const f32x4*>(ss + 64 + c * 4);
        xv = bn4(xv, sc, sh);
        *reinterpret_cast<f32x4*>(&xl[r][c * 4]) = xv;
    }
    __syncthreads();
    const int q = tid & 127, ng = tid >> 7;
    float acc[32] = {};
    for (int o4 = 0; o4 < 16; ++o4) {
        float w0 = Wt[4 * o4 + 0][q], w1 = Wt[4 * o4 + 1][q];
        float w2 = Wt[4 * o4 + 2][q], w3 = Wt[4 * o4 + 3][q];
#pragma unroll
        for (int k = 0; k < 32; ++k) {
            const f32x4 xv = *reinterpret_cast<const f32x4*>(&xl[ng + 2 * k][4 * o4]);
            acc[k] += xv.x * w0 + xv.y * w1 + xv.z * w2 + xv.w * w3;
        }
    }
    const float b = bl[q];
#pragma unroll
    for (int k = 0; k < 32; ++k)
        out[(size_t)(n0 + ng + 2 * k) * 128 + q] = acc[k] + b;
}

extern "C" void kernel_launch(void* const* d_in, const int* in_sizes, int n_in,
                              void* d_out, int out_size, void* d_ws, size_t ws_size,
                              hipStream_t stream) {
    const float* nf      = (const float*)d_in[0];
    const int*   ei      = (const int*)d_in[1];
    const float* ef      = (const float*)d_in[2];
    const float* W_edge0 = (const float*)d_in[4];
    const float* b_edge0 = (const float*)d_in[5];
    const float* W_root0 = (const float*)d_in[6];
    const float* b_root0 = (const float*)d_in[7];
    const float* gamma0  = (const float*)d_in[8];
    const float* beta0   = (const float*)d_in[9];
    const float* W_edge1 = (const float*)d_in[10];
    const float* b_edge1 = (const float*)d_in[11];
    const float* W_root1 = (const float*)d_in[12];
    const float* b_root1 = (const float*)d_in[13];
    const float* gamma1  = (const float*)d_in[14];
    const float* beta1   = (const float*)d_in[15];
    const float* W_lin   = (const float*)d_in[16];
    const float* b_lin   = (const float*)d_in[17];

    const int N = in_sizes[0] / 64;   // 8192
    const int E = in_sizes[1] / 2;    // 32768
    const int* src = ei;
    const int* dst = ei + E;

    unsigned short* ef_b = (unsigned short*)d_ws;          // E*64
    unsigned short* wbs0 = ef_b + (size_t)E * 64;          // 262144 (frag-order W0)
    unsigned short* wbs1 = wbs0 + 262144;                  // 262144
    float* aggr0 = (float*)(wbs1 + 262144);                // N*64
    float* aggr1 = aggr0 + (size_t)N * 64;                 // N*64
    float* NBbuf = aggr1 + (size_t)N * 64;                 // N*64
    float* stats = NBbuf + (size_t)N * 64;                 // 256
    float* ssbuf = stats + 256;                            // 256
    int*   cnt   = (int*)(ssbuf + 256);                    // 2

    const float invN = 1.0f / (float)N;
    const int na4 = E * 64 / 4;          // 524288

    prep<<<(na4 + 65536) / 256, 256, 0, stream>>>(ef, ef_b, na4, W_edge0, W_edge1,
                                                  wbs0, wbs1, stats, cnt);

    // ---- layer 0 ----
    node_mm2<<<dim3(N / 64, 2), 256, 0, stream>>>(nf, W_root0, b_root0, aggr0,
                                                  b_edge0, NBbuf, nullptr);
    msg_fused<<<dim3(E / 64, 4), 256, 0, stream>>>(ef_b, wbs0, nf, NBbuf, src, dst,
                                                   aggr0, nullptr);
    bn_stats<<<N / 128, 256, 0, stream>>>(aggr0, stats, gamma0, beta0, ssbuf,
                                          invN, cnt + 0, N / 128);

    // ---- layer 1 (x1 = BN(aggr0) applied on load everywhere) ----
    node_mm2<<<dim3(N / 64, 2), 256, 0, stream>>>(aggr0, W_root1, b_root1, aggr1,
                                                  b_edge1, NBbuf, ssbuf);
    msg_fused<<<dim3(E / 64, 4), 256, 0, stream>>>(ef_b, wbs1, aggr0, NBbuf, src, dst,
                                                   aggr1, ssbuf);
    bn_stats<<<N / 128, 256, 0, stream>>>(aggr1, stats + 128, gamma1, beta1, ssbuf + 128,
                                          invN, cnt + 1, N / 128);

    // ---- final linear (x2 = BN(aggr1) on load) ----
    out_kernel<<<N / 64, 256, 0, stream>>>(aggr1, W_lin, b_lin, (float*)d_out, ssbuf + 128);
}

// Round 7
// 173.396 us; speedup vs baseline: 2.9442x; 2.9442x over previous
//
#include <hip/hip_runtime.h>

typedef __bf16 bf16x8 __attribute__((ext_vector_type(8)));
typedef float f32x4 __attribute__((ext_vector_type(4)));

#define NEG_SLOPE 0.01f
#define BN_EPS 1e-5f

static __device__ __forceinline__ unsigned short f2bf(float f) {
    unsigned u = __builtin_bit_cast(unsigned, f);
    unsigned r = (u + 0x7fffu + ((u >> 16) & 1u)) >> 16;
    return (unsigned short)r;
}
static __device__ __forceinline__ float lrelu(float v) {
    return fmaxf(v, 0.f) + NEG_SLOPE * fminf(v, 0.f);
}
static __device__ __forceinline__ f32x4 bn4(f32x4 v, f32x4 sc, f32x4 sh) {
    f32x4 r = v * sc + sh;
    r.x = lrelu(r.x); r.y = lrelu(r.y); r.z = lrelu(r.z); r.w = lrelu(r.w);
    return r;
}

// ---- prep: convert ef to bf16 AND swizzle W_edge{0,1} into fragment order ----
// wbs[i][os][h][l][k] (shorts): lane l of o-slice os reads a CONTIGUOUS 16B
// A-frag: o = 16*os + (l&15), d = h*32 + 8*(l>>4) + k. 1KiB coalesced per wave.
__global__ __launch_bounds__(256) void prep(const float* __restrict__ ef,
                                            unsigned short* __restrict__ ef_b, int na4,
                                            const float* __restrict__ We0,
                                            const float* __restrict__ We1,
                                            unsigned short* __restrict__ wbs0,
                                            unsigned short* __restrict__ wbs1,
                                            float* __restrict__ stats,
                                            int* __restrict__ counters) {
    const int idx = blockIdx.x * 256 + threadIdx.x;
    if (blockIdx.x == 0) {
        stats[threadIdx.x] = 0.f;                  // stats[0..255]
        if (threadIdx.x < 2) counters[threadIdx.x] = 0;
    }
    if (idx < na4) {
        const f32x4 v = *reinterpret_cast<const f32x4*>(ef + (size_t)idx * 4);
        ushort4 u;
        u.x = f2bf(v.x); u.y = f2bf(v.y); u.z = f2bf(v.z); u.w = f2bf(v.w);
        *reinterpret_cast<ushort4*>(ef_b + (size_t)idx * 4) = u;
    } else {
        const int t = idx - na4;                   // 0..65535
        const float* We = (t >> 15) ? We1 : We0;
        unsigned short* wbs = (t >> 15) ? wbs1 : wbs0;
        const int r = t & 32767;                   // [i:6][os:2][h:1][l:6]
        const int i = r >> 9, os = (r >> 7) & 3, h = (r >> 6) & 1, l = r & 63;
        const float* sp = We + (size_t)(i * 64 + 16 * os + (l & 15)) * 64
                             + h * 32 + 8 * (l >> 4);
        const f32x4 v0 = *reinterpret_cast<const f32x4*>(sp);
        const f32x4 v1 = *reinterpret_cast<const f32x4*>(sp + 4);
        ushort4 u0, u1;
        u0.x = f2bf(v0.x); u0.y = f2bf(v0.y); u0.z = f2bf(v0.z); u0.w = f2bf(v0.w);
        u1.x = f2bf(v1.x); u1.y = f2bf(v1.y); u1.z = f2bf(v1.z); u1.w = f2bf(v1.w);
        *reinterpret_cast<ushort4*>(wbs + (size_t)r * 8) = u0;
        *reinterpret_cast<ushort4*>(wbs + (size_t)r * 8 + 4) = u1;
    }
}

// ---- root + node-bias matmuls; optional BN(x) on load ----
// y=0: aggr = BN(x)@Wr + br ; y=1: NB = BN(x)@be
__global__ __launch_bounds__(256) void node_mm2(const float* __restrict__ x,
                                                const float* __restrict__ Wr,
                                                const float* __restrict__ br,
                                                float* __restrict__ aggr,
                                                const float* __restrict__ be,
                                                float* __restrict__ NB,
                                                const float* __restrict__ ss) {
    const float* M; const float* bias; float* out;
    if (blockIdx.y == 0) { M = Wr; bias = br; out = aggr; }
    else                 { M = be; bias = nullptr; out = NB; }
    __shared__ float Ml[64][64];
    __shared__ float xl[64][64];
    const int tid = threadIdx.x;
    const int n0 = blockIdx.x * 64;
    for (int f = tid; f < 1024; f += 256) {
        int r = f >> 4, c = f & 15;
        *reinterpret_cast<float4*>(&Ml[r][c * 4]) =
            *reinterpret_cast<const float4*>(M + (size_t)r * 64 + c * 4);
        f32x4 xv = *reinterpret_cast<const f32x4*>(x + (size_t)(n0 + r) * 64 + c * 4);
        if (ss) {
            const f32x4 sc = *reinterpret_cast<const f32x4*>(ss + c * 4);
            const f32x4 sh = *reinterpret_cast<const f32x4*>(ss + 64 + c * 4);
            xv = bn4(xv, sc, sh);
        }
        *reinterpret_cast<f32x4*>(&xl[r][c * 4]) = xv;
    }
    __syncthreads();
    const int o = tid & 63, g = tid >> 6;
    float acc[16] = {};
    for (int i4 = 0; i4 < 16; ++i4) {
        float m0 = Ml[4 * i4 + 0][o], m1 = Ml[4 * i4 + 1][o];
        float m2 = Ml[4 * i4 + 2][o], m3 = Ml[4 * i4 + 3][o];
#pragma unroll
        for (int k = 0; k < 16; ++k) {
            const f32x4 xv = *reinterpret_cast<const f32x4*>(&xl[g + 4 * k][4 * i4]);
            acc[k] += xv.x * m0 + xv.y * m1 + xv.z * m2 + xv.w * m3;
        }
    }
    const float b = bias ? bias[o] : 0.f;
#pragma unroll
    for (int k = 0; k < 16; ++k)
        out[(size_t)(n0 + g + 4 * k) * 64 + o] = acc[k] + b;
}

// ---- fused NNConv message, o-split + fragment-order W + NAMED 4-deep prefetch ----
// Block = 64 edges x o-slice [16*by, 16*by+16). Wave w = 16-edge tile.
// Per i: D_i[o,e] = sum_d W_i[o,d]*ef[e,d] (2 MFMA); acc += x[src[e],i]*D_i.
__global__ __launch_bounds__(256, 6) void msg_fused(
    const unsigned short* __restrict__ ef_b,   // [E][64] bf16
    const unsigned short* __restrict__ wbs,    // fragment-order, see prep
    const float* __restrict__ x,               // [N][64] f32 (pre-BN if ss)
    const float* __restrict__ NB,              // [N][64] f32
    const int* __restrict__ src,
    const int* __restrict__ dst,
    float* __restrict__ aggr,                  // [N][64] f32
    const float* __restrict__ ss) {            // BN scale/shift for x, or null
    __shared__ float xT[64][64];               // xT[i][e] = BN(x)[src[e]][i]
    const int tid = threadIdx.x;
    const int e0 = blockIdx.x * 64;
    const int os = blockIdx.y;
    const int O0 = os * 16;

    // gather x rows of the 64 src nodes, transposed (f32, exact; BN on load)
#pragma unroll
    for (int it = 0; it < 4; ++it) {
        int f = it * 256 + tid;
        int e = f & 63, c = f >> 6;            // c in 0..15
        int s = src[e0 + e];
        f32x4 xv = *reinterpret_cast<const f32x4*>(x + (size_t)s * 64 + c * 4);
        if (ss) {
            const f32x4 sc = *reinterpret_cast<const f32x4*>(ss + c * 4);
            const f32x4 sh = *reinterpret_cast<const f32x4*>(ss + 64 + c * 4);
            xv = bn4(xv, sc, sh);
        }
        xT[4 * c + 0][e] = xv.x;
        xT[4 * c + 1][e] = xv.y;
        xT[4 * c + 2][e] = xv.z;
        xT[4 * c + 3][e] = xv.w;
    }

    const int w = tid >> 6, l = tid & 63, lg = l >> 4, ln = l & 15;
    const int ecol = 16 * w + ln;              // this lane's edge column

    // ef B-frag: wave's single 16-edge tile
    const unsigned short* pe = ef_b + (size_t)(e0 + ecol) * 64 + 8 * lg;
    const bf16x8 B0 = *reinterpret_cast<const bf16x8*>(pe);
    const bf16x8 B1 = *reinterpret_cast<const bf16x8*>(pe + 32);

    // W A-frags: contiguous 16B per lane, 1KiB coalesced per wave-load.
    // NAMED 4-deep prefetch slots (never runtime-indexed -> stay in VGPRs).
    const unsigned short* pwA = wbs + (size_t)os * 1024 + l * 8;   // i-stride 4096
#define LDA(i)  (*reinterpret_cast<const bf16x8*>(pwA + (size_t)(i) * 4096))
#define LDB_(i) (*reinterpret_cast<const bf16x8*>(pwA + (size_t)(i) * 4096 + 512))
    bf16x8 P0 = LDA(0), Q0 = LDB_(0);
    bf16x8 P1 = LDA(1), Q1 = LDB_(1);
    bf16x8 P2 = LDA(2), Q2 = LDB_(2);
    bf16x8 P3 = LDA(3), Q3 = LDB_(3);

    __syncthreads();

    f32x4 acc = {};
    for (int i = 0; i < 60; i += 4) {
        {
            f32x4 c = {};
            c = __builtin_amdgcn_mfma_f32_16x16x32_bf16(P0, B0, c, 0, 0, 0);
            c = __builtin_amdgcn_mfma_f32_16x16x32_bf16(Q0, B1, c, 0, 0, 0);
            P0 = LDA(i + 4); Q0 = LDB_(i + 4);
            acc += xT[i + 0][ecol] * c;
        }
        {
            f32x4 c = {};
            c = __builtin_amdgcn_mfma_f32_16x16x32_bf16(P1, B0, c, 0, 0, 0);
            c = __builtin_amdgcn_mfma_f32_16x16x32_bf16(Q1, B1, c, 0, 0, 0);
            P1 = LDA(i + 5); Q1 = LDB_(i + 5);
            acc += xT[i + 1][ecol] * c;
        }
        {
            f32x4 c = {};
            c = __builtin_amdgcn_mfma_f32_16x16x32_bf16(P2, B0, c, 0, 0, 0);
            c = __builtin_amdgcn_mfma_f32_16x16x32_bf16(Q2, B1, c, 0, 0, 0);
            P2 = LDA(i + 6); Q2 = LDB_(i + 6);
            acc += xT[i + 2][ecol] * c;
        }
        {
            f32x4 c = {};
            c = __builtin_amdgcn_mfma_f32_16x16x32_bf16(P3, B0, c, 0, 0, 0);
            c = __builtin_amdgcn_mfma_f32_16x16x32_bf16(Q3, B1, c, 0, 0, 0);
            P3 = LDA(i + 7); Q3 = LDB_(i + 7);
            acc += xT[i + 3][ecol] * c;
        }
    }
    // tail i = 60..63, no reloads
    {
        f32x4 c = {};
        c = __builtin_amdgcn_mfma_f32_16x16x32_bf16(P0, B0, c, 0, 0, 0);
        c = __builtin_amdgcn_mfma_f32_16x16x32_bf16(Q0, B1, c, 0, 0, 0);
        acc += xT[60][ecol] * c;
    }
    {
        f32x4 c = {};
        c = __builtin_amdgcn_mfma_f32_16x16x32_bf16(P1, B0, c, 0, 0, 0);
        c = __builtin_amdgcn_mfma_f32_16x16x32_bf16(Q1, B1, c, 0, 0, 0);
        acc += xT[61][ecol] * c;
    }
    {
        f32x4 c = {};
        c = __builtin_amdgcn_mfma_f32_16x16x32_bf16(P2, B0, c, 0, 0, 0);
        c = __builtin_amdgcn_mfma_f32_16x16x32_bf16(Q2, B1, c, 0, 0, 0);
        acc += xT[62][ecol] * c;
    }
    {
        f32x4 c = {};
        c = __builtin_amdgcn_mfma_f32_16x16x32_bf16(P3, B0, c, 0, 0, 0);
        c = __builtin_amdgcn_mfma_f32_16x16x32_bf16(Q3, B1, c, 0, 0, 0);
        acc += xT[63][ecol] * c;
    }
#undef LDA
#undef LDB_

    // epilogue: add NB[src][o-slice], scatter to aggr[dst][o-slice]
    const int e = e0 + ecol;
    const int s = src[e], d = dst[e];
    const f32x4 nbv = *reinterpret_cast<const f32x4*>(NB + (size_t)s * 64 + O0 + 4 * lg);
    const f32x4 add = acc + nbv;
#pragma unroll
    for (int rr = 0; rr < 4; ++rr)
        atomicAdd(aggr + (size_t)d * 64 + O0 + 4 * lg + rr, add[rr]);
}

// ---- BN statistics + last-block finalize (computes ss scale/shift) ----
__global__ __launch_bounds__(256) void bn_stats(const float* __restrict__ h,
                                                float* __restrict__ sums,
                                                const float* __restrict__ gamma,
                                                const float* __restrict__ beta,
                                                float* __restrict__ ss,
                                                float invN,
                                                int* __restrict__ counter,
                                                int nblk) {
    const int tid = threadIdx.x;
    const int o = tid & 63, g = tid >> 6;
    const int n0 = blockIdx.x * 128;
    float s = 0.f, s2 = 0.f;
    for (int k = 0; k < 32; ++k) {
        float v = h[(size_t)(n0 + g * 32 + k) * 64 + o];
        s += v; s2 += v * v;
    }
    __shared__ float red[2][4][64];
    __shared__ int lastFlag;
    red[0][g][o] = s; red[1][g][o] = s2;
    __syncthreads();
    if (g == 0) {
        s  = red[0][0][o] + red[0][1][o] + red[0][2][o] + red[0][3][o];
        s2 = red[1][0][o] + red[1][1][o] + red[1][2][o] + red[1][3][o];
        atomicAdd(&sums[o], s);
        atomicAdd(&sums[64 + o], s2);
    }
    __threadfence();
    __syncthreads();
    if (tid == 0) lastFlag = (atomicAdd(counter, 1) == nblk - 1);
    __syncthreads();
    if (lastFlag && tid < 64) {
        const float sv  = atomicAdd(&sums[tid], 0.f);        // coherent read
        const float sv2 = atomicAdd(&sums[64 + tid], 0.f);
        const float mean = sv * invN;
        const float var  = sv2 * invN - mean * mean;
        const float sc = gamma[tid] * rsqrtf(var + BN_EPS);
        ss[tid] = sc;
        ss[64 + tid] = beta[tid] - mean * sc;
    }
}

// ---- final: out[n,q] = sum_o BN(x)[n,o]*W_lin[q,o] + b_lin[q] ----
__global__ __launch_bounds__(256) void out_kernel(const float* __restrict__ x2,
                                                  const float* __restrict__ Wl,
                                                  const float* __restrict__ bl,
                                                  float* __restrict__ out,
                                                  const float* __restrict__ ss) {
    __shared__ float Wt[64][129];
    __shared__ float xl[64][64];
    const int tid = threadIdx.x;
    const int n0 = blockIdx.x * 64;
    for (int f = tid; f < 8192; f += 256) {
        int q = f >> 6, o = f & 63;
        Wt[o][q] = Wl[f];
    }
    for (int f = tid; f < 1024; f += 256) {
        int r = f >> 4, c = f & 15;
        f32x4 xv = *reinterpret_cast<const f32x4*>(x2 + (size_t)(n0 + r) * 64 + c * 4);
        const f32x4 sc = *reinterpret_cast<const f32x4*>(ss + c * 4);
        const f32x4 sh = *reinterpret_cast<const f32x4*>(ss + 64 + c * 4);
        xv = bn4(xv, sc, sh);
        *reinterpret_cast<f32x4*>(&xl[r][c * 4]) = xv;
    }
    __syncthreads();
    const int q = tid & 127, ng = tid >> 7;
    float acc[32] = {};
    for (int o4 = 0; o4 < 16; ++o4) {
        float w0 = Wt[4 * o4 + 0][q], w1 = Wt[4 * o4 + 1][q];
        float w2 = Wt[4 * o4 + 2][q], w3 = Wt[4 * o4 + 3][q];
#pragma unroll
        for (int k = 0; k < 32; ++k) {
            const f32x4 xv = *reinterpret_cast<const f32x4*>(&xl[ng + 2 * k][4 * o4]);
            acc[k] += xv.x * w0 + xv.y * w1 + xv.z * w2 + xv.w * w3;
        }
    }
    const float b = bl[q];
#pragma unroll
    for (int k = 0; k < 32; ++k)
        out[(size_t)(n0 + ng + 2 * k) * 128 + q] = acc[k] + b;
}

extern "C" void kernel_launch(void* const* d_in, const int* in_sizes, int n_in,
                              void* d_out, int out_size, void* d_ws, size_t ws_size,
                              hipStream_t stream) {
    const float* nf      = (const float*)d_in[0];
    const int*   ei      = (const int*)d_in[1];
    const float* ef      = (const float*)d_in[2];
    const float* W_edge0 = (const float*)d_in[4];
    const float* b_edge0 = (const float*)d_in[5];
    const float* W_root0 = (const float*)d_in[6];
    const float* b_root0 = (const float*)d_in[7];
    const float* gamma0  = (const float*)d_in[8];
    const float* beta0   = (const float*)d_in[9];
    const float* W_edge1 = (const float*)d_in[10];
    const float* b_edge1 = (const float*)d_in[11];
    const float* W_root1 = (const float*)d_in[12];
    const float* b_root1 = (const float*)d_in[13];
    const float* gamma1  = (const float*)d_in[14];
    const float* beta1   = (const float*)d_in[15];
    const float* W_lin   = (const float*)d_in[16];
    const float* b_lin   = (const float*)d_in[17];

    const int N = in_sizes[0] / 64;   // 8192
    const int E = in_sizes[1] / 2;    // 32768
    const int* src = ei;
    const int* dst = ei + E;

    unsigned short* ef_b = (unsigned short*)d_ws;          // E*64
    unsigned short* wbs0 = ef_b + (size_t)E * 64;          // 262144 (frag-order W0)
    unsigned short* wbs1 = wbs0 + 262144;                  // 262144
    float* aggr0 = (float*)(wbs1 + 262144);                // N*64
    float* aggr1 = aggr0 + (size_t)N * 64;                 // N*64
    float* NBbuf = aggr1 + (size_t)N * 64;                 // N*64
    float* stats = NBbuf + (size_t)N * 64;                 // 256
    float* ssbuf = stats + 256;                            // 256
    int*   cnt   = (int*)(ssbuf + 256);                    // 2

    const float invN = 1.0f / (float)N;
    const int na4 = E * 64 / 4;          // 524288

    prep<<<(na4 + 65536) / 256, 256, 0, stream>>>(ef, ef_b, na4, W_edge0, W_edge1,
                                                  wbs0, wbs1, stats, cnt);

    // ---- layer 0 ----
    node_mm2<<<dim3(N / 64, 2), 256, 0, stream>>>(nf, W_root0, b_root0, aggr0,
                                                  b_edge0, NBbuf, nullptr);
    msg_fused<<<dim3(E / 64, 4), 256, 0, stream>>>(ef_b, wbs0, nf, NBbuf, src, dst,
                                                   aggr0, nullptr);
    bn_stats<<<N / 128, 256, 0, stream>>>(aggr0, stats, gamma0, beta0, ssbuf,
                                          invN, cnt + 0, N / 128);

    // ---- layer 1 (x1 = BN(aggr0) applied on load everywhere) ----
    node_mm2<<<dim3(N / 64, 2), 256, 0, stream>>>(aggr0, W_root1, b_root1, aggr1,
                                                  b_edge1, NBbuf, ssbuf);
    msg_fused<<<dim3(E / 64, 4), 256, 0, stream>>>(ef_b, wbs1, aggr0, NBbuf, src, dst,
                                                   aggr1, ssbuf);
    bn_stats<<<N / 128, 256, 0, stream>>>(aggr1, stats + 128, gamma1, beta1, ssbuf + 128,
                                          invN, cnt + 1, N / 128);

    // ---- final linear (x2 = BN(aggr1) on load) ----
    out_kernel<<<N / 64, 256, 0, stream>>>(aggr1, W_lin, b_lin, (float*)d_out, ssbuf + 128);
}

// Round 8
// 166.213 us; speedup vs baseline: 3.0715x; 1.0432x over previous
//
#include <hip/hip_runtime.h>

typedef __bf16 bf16x8 __attribute__((ext_vector_type(8)));
typedef float f32x4 __attribute__((ext_vector_type(4)));

#define NEG_SLOPE 0.01f
#define BN_EPS 1e-5f

static __device__ __forceinline__ unsigned short f2bf(float f) {
    unsigned u = __builtin_bit_cast(unsigned, f);
    unsigned r = (u + 0x7fffu + ((u >> 16) & 1u)) >> 16;
    return (unsigned short)r;
}
static __device__ __forceinline__ float lrelu(float v) {
    return fmaxf(v, 0.f) + NEG_SLOPE * fminf(v, 0.f);
}
static __device__ __forceinline__ f32x4 bn4(f32x4 v, f32x4 sc, f32x4 sh) {
    f32x4 r = v * sc + sh;
    r.x = lrelu(r.x); r.y = lrelu(r.y); r.z = lrelu(r.z); r.w = lrelu(r.w);
    return r;
}
// async global->LDS, 16B per lane (dest must be uniform base + lane*16)
static __device__ __forceinline__ void gl16(const void* g, void* l) {
    __builtin_amdgcn_global_load_lds(
        (const __attribute__((address_space(1))) void*)g,
        (__attribute__((address_space(3))) void*)l, 16, 0, 0);
}

// ---- prep: convert ef to bf16 AND swizzle W_edge{0,1} into fragment order ----
// wbs[i][os][h][l][8] (shorts): lane l of o-slice os reads a CONTIGUOUS 16B
// A-frag: o = 16*os + (l&15), d = h*32 + 8*(l>>4) + k. 1KiB coalesced per wave.
__global__ __launch_bounds__(256) void prep(const float* __restrict__ ef,
                                            unsigned short* __restrict__ ef_b, int na4,
                                            const float* __restrict__ We0,
                                            const float* __restrict__ We1,
                                            unsigned short* __restrict__ wbs0,
                                            unsigned short* __restrict__ wbs1,
                                            float* __restrict__ stats,
                                            int* __restrict__ counters) {
    const int idx = blockIdx.x * 256 + threadIdx.x;
    if (blockIdx.x == 0) {
        stats[threadIdx.x] = 0.f;                  // stats[0..255]
        if (threadIdx.x < 2) counters[threadIdx.x] = 0;
    }
    if (idx < na4) {
        const f32x4 v = *reinterpret_cast<const f32x4*>(ef + (size_t)idx * 4);
        ushort4 u;
        u.x = f2bf(v.x); u.y = f2bf(v.y); u.z = f2bf(v.z); u.w = f2bf(v.w);
        *reinterpret_cast<ushort4*>(ef_b + (size_t)idx * 4) = u;
    } else {
        const int t = idx - na4;                   // 0..65535
        const float* We = (t >> 15) ? We1 : We0;
        unsigned short* wbs = (t >> 15) ? wbs1 : wbs0;
        const int r = t & 32767;                   // [i:6][os:2][h:1][l:6]
        const int i = r >> 9, os = (r >> 7) & 3, h = (r >> 6) & 1, l = r & 63;
        const float* sp = We + (size_t)(i * 64 + 16 * os + (l & 15)) * 64
                             + h * 32 + 8 * (l >> 4);
        const f32x4 v0 = *reinterpret_cast<const f32x4*>(sp);
        const f32x4 v1 = *reinterpret_cast<const f32x4*>(sp + 4);
        ushort4 u0, u1;
        u0.x = f2bf(v0.x); u0.y = f2bf(v0.y); u0.z = f2bf(v0.z); u0.w = f2bf(v0.w);
        u1.x = f2bf(v1.x); u1.y = f2bf(v1.y); u1.z = f2bf(v1.z); u1.w = f2bf(v1.w);
        *reinterpret_cast<ushort4*>(wbs + (size_t)r * 8) = u0;
        *reinterpret_cast<ushort4*>(wbs + (size_t)r * 8 + 4) = u1;
    }
}

// ---- root + node-bias matmuls; optional BN(x) on load ----
// y=0: aggr = BN(x)@Wr + br ; y=1: NB = BN(x)@be
__global__ __launch_bounds__(256) void node_mm2(const float* __restrict__ x,
                                                const float* __restrict__ Wr,
                                                const float* __restrict__ br,
                                                float* __restrict__ aggr,
                                                const float* __restrict__ be,
                                                float* __restrict__ NB,
                                                const float* __restrict__ ss) {
    const float* M; const float* bias; float* out;
    if (blockIdx.y == 0) { M = Wr; bias = br; out = aggr; }
    else                 { M = be; bias = nullptr; out = NB; }
    __shared__ float Ml[64][64];
    __shared__ float xl[64][64];
    const int tid = threadIdx.x;
    const int n0 = blockIdx.x * 64;
    for (int f = tid; f < 1024; f += 256) {
        int r = f >> 4, c = f & 15;
        *reinterpret_cast<float4*>(&Ml[r][c * 4]) =
            *reinterpret_cast<const float4*>(M + (size_t)r * 64 + c * 4);
        f32x4 xv = *reinterpret_cast<const f32x4*>(x + (size_t)(n0 + r) * 64 + c * 4);
        if (ss) {
            const f32x4 sc = *reinterpret_cast<const f32x4*>(ss + c * 4);
            const f32x4 sh = *reinterpret_cast<const f32x4*>(ss + 64 + c * 4);
            xv = bn4(xv, sc, sh);
        }
        *reinterpret_cast<f32x4*>(&xl[r][c * 4]) = xv;
    }
    __syncthreads();
    const int o = tid & 63, g = tid >> 6;
    float acc[16] = {};
    for (int i4 = 0; i4 < 16; ++i4) {
        float m0 = Ml[4 * i4 + 0][o], m1 = Ml[4 * i4 + 1][o];
        float m2 = Ml[4 * i4 + 2][o], m3 = Ml[4 * i4 + 3][o];
#pragma unroll
        for (int k = 0; k < 16; ++k) {
            const f32x4 xv = *reinterpret_cast<const f32x4*>(&xl[g + 4 * k][4 * i4]);
            acc[k] += xv.x * m0 + xv.y * m1 + xv.z * m2 + xv.w * m3;
        }
    }
    const float b = bias ? bias[o] : 0.f;
#pragma unroll
    for (int k = 0; k < 16; ++k)
        out[(size_t)(n0 + g + 4 * k) * 64 + o] = acc[k] + b;
}

// ---- fused NNConv message: 64 edges/block, full-o (wave w = o-slice w),
// W streamed through LDS in 4-i chunks via global_load_lds + double buffer.
// Per i per wave: 2 ds_read_b128 A-frags + 1 ds_read_b128 xs + 8 MFMA + 16 fmac.
__global__ __launch_bounds__(256, 2) void msg_fused(
    const unsigned short* __restrict__ ef_b,   // [E][64] bf16
    const unsigned short* __restrict__ wbs,    // fragment-order [i][os][h][l][8]
    const float* __restrict__ x,               // [N][64] f32 (pre-BN if ss)
    const float* __restrict__ NB,              // [N][64] f32
    const int* __restrict__ src,
    const int* __restrict__ dst,
    float* __restrict__ aggr,                  // [N][64] f32
    const float* __restrict__ ss) {            // BN scale/shift for x, or null
    extern __shared__ char smem[];
    unsigned short* wlds = (unsigned short*)smem;   // [2][16384] shorts = 64KB
    float* xT2 = (float*)(smem + 65536);            // [64][16][4] = 16KB
    const int tid = threadIdx.x;
    const int e0 = blockIdx.x * 64;

    // gather x rows of the 64 src nodes -> xT2[i][ln][t] (f32, BN on load)
#pragma unroll
    for (int it = 0; it < 4; ++it) {
        int f = it * 256 + tid;
        int e = f & 63, c = f >> 6;            // c in 0..15
        int s = src[e0 + e];
        f32x4 xv = *reinterpret_cast<const f32x4*>(x + (size_t)s * 64 + c * 4);
        if (ss) {
            const f32x4 sc = *reinterpret_cast<const f32x4*>(ss + c * 4);
            const f32x4 sh = *reinterpret_cast<const f32x4*>(ss + 64 + c * 4);
            xv = bn4(xv, sc, sh);
        }
        const int eln = e & 15, ett = e >> 4;
        xT2[(4 * c + 0) * 64 + eln * 4 + ett] = xv.x;
        xT2[(4 * c + 1) * 64 + eln * 4 + ett] = xv.y;
        xT2[(4 * c + 2) * 64 + eln * 4 + ett] = xv.z;
        xT2[(4 * c + 3) * 64 + eln * 4 + ett] = xv.w;
    }

    const int w = tid >> 6, l = tid & 63, lg = l >> 4, ln = l & 15;

    // ef B-frags: wave covers all 4 edge-tiles of the block (held in regs)
    bf16x8 B0[4], B1[4];
#pragma unroll
    for (int tt = 0; tt < 4; ++tt) {
        const unsigned short* pe = ef_b + (size_t)(e0 + 16 * tt + ln) * 64 + 8 * lg;
        B0[tt] = *reinterpret_cast<const bf16x8*>(pe);
        B1[tt] = *reinterpret_cast<const bf16x8*>(pe + 32);
    }

    // stage chunk 0 (4 i = 32KB, linear copy, 8 x 16B per thread)
#pragma unroll
    for (int j = 0; j < 8; ++j)
        gl16(wbs + j * 2048 + tid * 8, wlds + j * 2048 + tid * 8);

    __syncthreads();   // drains gather ds_writes + chunk-0 vmcnt

    f32x4 acc[4] = {};
    int buf = 0;
    for (int t = 0; t < 16; ++t) {
        if (t < 15) {                          // stage next chunk async
            const unsigned short* gsrc = wbs + (size_t)(t + 1) * 16384;
            unsigned short* ldst = wlds + (buf ^ 1) * 16384;
#pragma unroll
            for (int j = 0; j < 8; ++j)
                gl16(gsrc + j * 2048 + tid * 8, ldst + j * 2048 + tid * 8);
        }
        // compute 4 i from current chunk
        const unsigned short* wb_ = wlds + buf * 16384 + w * 1024 + l * 8;
#pragma unroll
        for (int ii = 0; ii < 4; ++ii) {
            const bf16x8 A0 = *reinterpret_cast<const bf16x8*>(wb_ + ii * 4096);
            const bf16x8 A1 = *reinterpret_cast<const bf16x8*>(wb_ + ii * 4096 + 512);
            const f32x4 xs = *reinterpret_cast<const f32x4*>(&xT2[(t * 4 + ii) * 64 + ln * 4]);
#pragma unroll
            for (int tt = 0; tt < 4; ++tt) {
                f32x4 c = {};
                c = __builtin_amdgcn_mfma_f32_16x16x32_bf16(A0, B0[tt], c, 0, 0, 0);
                c = __builtin_amdgcn_mfma_f32_16x16x32_bf16(A1, B1[tt], c, 0, 0, 0);
                acc[tt] += xs[tt] * c;
            }
        }
        __syncthreads();                       // next chunk staged + buf free
        buf ^= 1;
    }

    // epilogue: add NB[src][o-slice w], scatter to aggr[dst]
#pragma unroll
    for (int tt = 0; tt < 4; ++tt) {
        const int e = e0 + 16 * tt + ln;
        const int s = src[e], d = dst[e];
        const f32x4 nbv = *reinterpret_cast<const f32x4*>(NB + (size_t)s * 64 + 16 * w + 4 * lg);
        const f32x4 add = acc[tt] + nbv;
#pragma unroll
        for (int rr = 0; rr < 4; ++rr)
            atomicAdd(aggr + (size_t)d * 64 + 16 * w + 4 * lg + rr, add[rr]);
    }
}

// ---- BN statistics + last-block finalize (computes ss scale/shift) ----
__global__ __launch_bounds__(256) void bn_stats(const float* __restrict__ h,
                                                float* __restrict__ sums,
                                                const float* __restrict__ gamma,
                                                const float* __restrict__ beta,
                                                float* __restrict__ ss,
                                                float invN,
                                                int* __restrict__ counter,
                                                int nblk) {
    const int tid = threadIdx.x;
    const int o = tid & 63, g = tid >> 6;
    const int n0 = blockIdx.x * 128;
    float s = 0.f, s2 = 0.f;
    for (int k = 0; k < 32; ++k) {
        float v = h[(size_t)(n0 + g * 32 + k) * 64 + o];
        s += v; s2 += v * v;
    }
    __shared__ float red[2][4][64];
    __shared__ int lastFlag;
    red[0][g][o] = s; red[1][g][o] = s2;
    __syncthreads();
    if (g == 0) {
        s  = red[0][0][o] + red[0][1][o] + red[0][2][o] + red[0][3][o];
        s2 = red[1][0][o] + red[1][1][o] + red[1][2][o] + red[1][3][o];
        atomicAdd(&sums[o], s);
        atomicAdd(&sums[64 + o], s2);
    }
    __threadfence();
    __syncthreads();
    if (tid == 0) lastFlag = (atomicAdd(counter, 1) == nblk - 1);
    __syncthreads();
    if (lastFlag && tid < 64) {
        const float sv  = atomicAdd(&sums[tid], 0.f);        // coherent read
        const float sv2 = atomicAdd(&sums[64 + tid], 0.f);
        const float mean = sv * invN;
        const float var  = sv2 * invN - mean * mean;
        const float sc = gamma[tid] * rsqrtf(var + BN_EPS);
        ss[tid] = sc;
        ss[64 + tid] = beta[tid] - mean * sc;
    }
}

// ---- final: out[n,q] = sum_o BN(x)[n,o]*W_lin[q,o] + b_lin[q] ----
__global__ __launch_bounds__(256) void out_kernel(const float* __restrict__ x2,
                                                  const float* __restrict__ Wl,
                                                  const float* __restrict__ bl,
                                                  float* __restrict__ out,
                                                  const float* __restrict__ ss) {
    __shared__ float Wt[64][129];
    __shared__ float xl[64][64];
    const int tid = threadIdx.x;
    const int n0 = blockIdx.x * 64;
    for (int f = tid; f < 8192; f += 256) {
        int q = f >> 6, o = f & 63;
        Wt[o][q] = Wl[f];
    }
    for (int f = tid; f < 1024; f += 256) {
        int r = f >> 4, c = f & 15;
        f32x4 xv = *reinterpret_cast<const f32x4*>(x2 + (size_t)(n0 + r) * 64 + c * 4);
        const f32x4 sc = *reinterpret_cast<const f32x4*>(ss + c * 4);
        const f32x4 sh = *reinterpret_cast<const f32x4*>(ss + 64 + c * 4);
        xv = bn4(xv, sc, sh);
        *reinterpret_cast<f32x4*>(&xl[r][c * 4]) = xv;
    }
    __syncthreads();
    const int q = tid & 127, ng = tid >> 7;
    float acc[32] = {};
    for (int o4 = 0; o4 < 16; ++o4) {
        float w0 = Wt[4 * o4 + 0][q], w1 = Wt[4 * o4 + 1][q];
        float w2 = Wt[4 * o4 + 2][q], w3 = Wt[4 * o4 + 3][q];
#pragma unroll
        for (int k = 0; k < 32; ++k) {
            const f32x4 xv = *reinterpret_cast<const f32x4*>(&xl[ng + 2 * k][4 * o4]);
            acc[k] += xv.x * w0 + xv.y * w1 + xv.z * w2 + xv.w * w3;
        }
    }
    const float b = bl[q];
#pragma unroll
    for (int k = 0; k < 32; ++k)
        out[(size_t)(n0 + ng + 2 * k) * 128 + q] = acc[k] + b;
}

extern "C" void kernel_launch(void* const* d_in, const int* in_sizes, int n_in,
                              void* d_out, int out_size, void* d_ws, size_t ws_size,
                              hipStream_t stream) {
    const float* nf      = (const float*)d_in[0];
    const int*   ei      = (const int*)d_in[1];
    const float* ef      = (const float*)d_in[2];
    const float* W_edge0 = (const float*)d_in[4];
    const float* b_edge0 = (const float*)d_in[5];
    const float* W_root0 = (const float*)d_in[6];
    const float* b_root0 = (const float*)d_in[7];
    const float* gamma0  = (const float*)d_in[8];
    const float* beta0   = (const float*)d_in[9];
    const float* W_edge1 = (const float*)d_in[10];
    const float* b_edge1 = (const float*)d_in[11];
    const float* W_root1 = (const float*)d_in[12];
    const float* b_root1 = (const float*)d_in[13];
    const float* gamma1  = (const float*)d_in[14];
    const float* beta1   = (const float*)d_in[15];
    const float* W_lin   = (const float*)d_in[16];
    const float* b_lin   = (const float*)d_in[17];

    const int N = in_sizes[0] / 64;   // 8192
    const int E = in_sizes[1] / 2;    // 32768
    const int* src = ei;
    const int* dst = ei + E;

    unsigned short* ef_b = (unsigned short*)d_ws;          // E*64
    unsigned short* wbs0 = ef_b + (size_t)E * 64;          // 262144 (frag-order W0)
    unsigned short* wbs1 = wbs0 + 262144;                  // 262144
    float* aggr0 = (float*)(wbs1 + 262144);                // N*64
    float* aggr1 = aggr0 + (size_t)N * 64;                 // N*64
    float* NBbuf = aggr1 + (size_t)N * 64;                 // N*64
    float* stats = NBbuf + (size_t)N * 64;                 // 256
    float* ssbuf = stats + 256;                            // 256
    int*   cnt   = (int*)(ssbuf + 256);                    // 2

    const float invN = 1.0f / (float)N;
    const int na4 = E * 64 / 4;          // 524288
    const int SMEM = 81920;              // 64KB W dbuf + 16KB xT2

    prep<<<(na4 + 65536) / 256, 256, 0, stream>>>(ef, ef_b, na4, W_edge0, W_edge1,
                                                  wbs0, wbs1, stats, cnt);

    // ---- layer 0 ----
    node_mm2<<<dim3(N / 64, 2), 256, 0, stream>>>(nf, W_root0, b_root0, aggr0,
                                                  b_edge0, NBbuf, nullptr);
    msg_fused<<<E / 64, 256, SMEM, stream>>>(ef_b, wbs0, nf, NBbuf, src, dst,
                                             aggr0, nullptr);
    bn_stats<<<N / 128, 256, 0, stream>>>(aggr0, stats, gamma0, beta0, ssbuf,
                                          invN, cnt + 0, N / 128);

    // ---- layer 1 (x1 = BN(aggr0) applied on load everywhere) ----
    node_mm2<<<dim3(N / 64, 2), 256, 0, stream>>>(aggr0, W_root1, b_root1, aggr1,
                                                  b_edge1, NBbuf, ssbuf);
    msg_fused<<<E / 64, 256, SMEM, stream>>>(ef_b, wbs1, aggr0, NBbuf, src, dst,
                                             aggr1, ssbuf);
    bn_stats<<<N / 128, 256, 0, stream>>>(aggr1, stats + 128, gamma1, beta1, ssbuf + 128,
                                          invN, cnt + 1, N / 128);

    // ---- final linear (x2 = BN(aggr1) on load) ----
    out_kernel<<<N / 64, 256, 0, stream>>>(aggr1, W_lin, b_lin, (float*)d_out, ssbuf + 128);
}